// Round 1
// 888.271 us; speedup vs baseline: 1.0069x; 1.0069x over previous
//
#include <hip/hip_runtime.h>
#include <math.h>

#define PADID 400000

typedef __attribute__((ext_vector_type(8))) short bf16x8;
typedef __attribute__((ext_vector_type(4))) float f32x4;

__device__ __forceinline__ float sigmoidf_(float x){ return 1.0f/(1.0f+__expf(-x)); }
__device__ __forceinline__ float ftanh(float x){ return 1.0f - 2.0f/(__expf(2.0f*x)+1.0f); }

__device__ __forceinline__ unsigned short f2bf(float f){
    unsigned u = __float_as_uint(f);
    u += 0x7FFFu + ((u >> 16) & 1u);
    return (unsigned short)(u >> 16);
}
__device__ __forceinline__ float bf2f(unsigned short s){
    return __uint_as_float(((unsigned)s) << 16);
}

// gate-interleaved permutation: m' -> original gate-major row
__device__ __forceinline__ int perm_orig(int mp){
    int gate = (mp >> 4) & 3;
    int j = (mp >> 6) * 16 + (mp & 15);
    return gate * 1024 + j;
}

// ---------------------------------------------------------------------------
// Weight preconversion fp32 -> bf16 + permutations (one pass).
// ---------------------------------------------------------------------------
__global__ __launch_bounds__(256) void preconvert(
    const float* __restrict__ gcnW, const float* __restrict__ p1W,
    const float* __restrict__ p2W, const float* __restrict__ Wih,
    const float* __restrict__ Whh, const float* __restrict__ b_ih,
    const float* __restrict__ b_hh,
    unsigned short* __restrict__ wgcn, unsigned short* __restrict__ p1w,
    unsigned short* __restrict__ p2w, unsigned short* __restrict__ wih_p,
    unsigned short* __restrict__ whh_p, float* __restrict__ bias0_p)
{
    long long i = ((long long)blockIdx.x * 256 + threadIdx.x) * 4;
    float4 v;
    if (i < 131072LL) {
        v = *(const float4*)(gcnW + i);
        unsigned a0 = f2bf(v.x) | ((unsigned)f2bf(v.y) << 16);
        unsigned a1 = f2bf(v.z) | ((unsigned)f2bf(v.w) << 16);
        *(uint2*)(wgcn + i) = make_uint2(a0, a1);
    } else if (i < 655360LL) {
        long long off = i - 131072LL;
        v = *(const float4*)(p1W + off);
        unsigned a0 = f2bf(v.x) | ((unsigned)f2bf(v.y) << 16);
        unsigned a1 = f2bf(v.z) | ((unsigned)f2bf(v.w) << 16);
        *(uint2*)(p1w + off) = make_uint2(a0, a1);
    } else if (i < 1179648LL) {
        long long off = i - 655360LL;
        v = *(const float4*)(p2W + off);
        unsigned a0 = f2bf(v.x) | ((unsigned)f2bf(v.y) << 16);
        unsigned a1 = f2bf(v.z) | ((unsigned)f2bf(v.w) << 16);
        *(uint2*)(p2w + off) = make_uint2(a0, a1);
    } else if (i < 3276800LL) {
        long long off = i - 1179648LL;
        int mp = (int)(off >> 9), col = (int)(off & 511);
        int orig = perm_orig(mp);
        v = *(const float4*)(Wih + (long long)orig * 512 + col);
        unsigned a0 = f2bf(v.x) | ((unsigned)f2bf(v.y) << 16);
        unsigned a1 = f2bf(v.z) | ((unsigned)f2bf(v.w) << 16);
        *(uint2*)(wih_p + off) = make_uint2(a0, a1);
    } else if (i < 5373952LL) {
        long long off = i - 3276800LL;
        int mp = (int)(off >> 9), col = (int)(off & 511);
        int orig = perm_orig(mp);
        v = *(const float4*)(Whh + (long long)orig * 1024 + col);
        unsigned a0 = f2bf(v.x) | ((unsigned)f2bf(v.y) << 16);
        unsigned a1 = f2bf(v.z) | ((unsigned)f2bf(v.w) << 16);
        *(uint2*)(whh_p + off) = make_uint2(a0, a1);
    } else if (i < 5378048LL) {
        long long off = i - 5373952LL;
        #pragma unroll
        for (int q = 0; q < 4; q++) {
            int mp = (int)off + q;
            int orig = perm_orig(mp);
            bias0_p[mp] = b_ih[orig] + b_hh[orig];
        }
    }
}

// ---------------------------------------------------------------------------
// Neighbor encoder, 2 samples/block. A = gathered emb rows (128 x 512 bf16),
// B = gcn_W bf16 (256 x 512). 4 waves, each 64 rows x 128 cols.
// T14 async-STAGE split: A-gather for channel ch+1 is issued into registers
// right after the staging barrier of channel ch, so HBM-random gather latency
// (~900 cyc) hides under ch's MFMA phase + next B-stage instead of stalling
// the wave inside the phase.
// ---------------------------------------------------------------------------
__device__ __forceinline__ void ne_decode(int s,
    const int* q_l1, const int* q_deg_l, const int* q_r1, const int* q_deg_r,
    const int* s_l1, const int* s_deg_l, const int* s_r1, const int* s_deg_r,
    const int* query, const int* support,
    const int*& conn, const int*& deg, const int*& ids, int& n, int& ids_off, int& row, int& col)
{
    if (s < 2048)      { conn = q_l1; deg = q_deg_l; ids = query;   n = s;      ids_off = 0; row = s;        col = 0;   }
    else if (s < 4096) { conn = q_r1; deg = q_deg_r; ids = query;   n = s-2048; ids_off = 1; row = s-2048;   col = 256; }
    else if (s < 4101) { conn = s_l1; deg = s_deg_l; ids = support; n = s-4096; ids_off = 0; row = 2048+n;   col = 0;   }
    else               { conn = s_r1; deg = s_deg_r; ids = support; n = s-4101; ids_off = 1; row = 2048+n;   col = 256; }
}

__global__ __launch_bounds__(256, 2) void ne_fused(
    const float* __restrict__ emb, const unsigned short* __restrict__ Wbf,
    const float* __restrict__ wb, const float* __restrict__ bb,
    const float* __restrict__ gate_w, const float* __restrict__ gate_temp,
    const int* __restrict__ q_l1, const int* __restrict__ q_deg_l,
    const int* __restrict__ q_r1, const int* __restrict__ q_deg_r,
    const int* __restrict__ s_l1, const int* __restrict__ s_deg_l,
    const int* __restrict__ s_r1, const int* __restrict__ s_deg_r,
    const int* __restrict__ query, const int* __restrict__ support,
    unsigned short* __restrict__ vec_bf)
{
    __shared__ int   rel_s[128];
    __shared__ int   ent_s[128];
    __shared__ unsigned short A_lds[128 * 72];
    __shared__ unsigned short B_lds[256 * 72];
    __shared__ float red[4][4][128];
    __shared__ float gw_s[128];
    __shared__ float gate_sh[2];

    const int bid = blockIdx.x;
    const int t = threadIdx.x;
    const int lane = t & 63, w = t >> 6, lr = lane & 15, kg = lane >> 4;
    const int si_w = w >> 1;            // which sample this wave computes
    const int wc0 = (w & 1) * 128;      // col base of this wave

    // load conn for both samples
    {
        int si = t >> 7, u = t & 127;
        const int *conn, *deg, *ids; int n, ids_off, row, col;
        ne_decode(bid*2 + si, q_l1,q_deg_l,q_r1,q_deg_r,s_l1,s_deg_l,s_r1,s_deg_r,
                  query, support, conn, deg, ids, n, ids_off, row, col);
        int v = conn[n*128 + u];
        if (u & 1) ent_s[si*64 + (u>>1)] = v; else rel_s[si*64 + (u>>1)] = v;
    }
    __syncthreads();

    const int rr = t >> 1, half = t & 1;  // A-stage: row 0..127, col half

    // ---- pipelined A-gather staging registers ----
    float4 a_reg[8];
    #define ISSUE_A(ch_) { \
        const int side_ = ((ch_) >= 4); \
        const int cg0_ = ((ch_) & 3) * 64; \
        int rowid_ = side_ ? ent_s[rr] : rel_s[rr]; \
        const float* src_ = emb + (long long)rowid_ * 256 + cg0_ + half * 32; \
        _Pragma("unroll") \
        for (int q_ = 0; q_ < 8; q_++) a_reg[q_] = *(const float4*)(src_ + q_*4); \
    }

    // issue A(0) immediately; latency hides under gate-weight gather + B(0) stage
    ISSUE_A(0);

    if (t < 128) {
        int r = rel_s[t];
        gw_s[t] = gate_w[(r == PADID) ? 0 : r];
    }
    __syncthreads();
    if ((t & 63) == 0 && t < 128) {
        int si = t >> 6;
        const int *conn, *deg, *ids; int n, ids_off, row, col;
        ne_decode(bid*2 + si, q_l1,q_deg_l,q_r1,q_deg_r,s_l1,s_deg_l,s_r1,s_deg_r,
                  query, support, conn, deg, ids, n, ids_off, row, col);
        float s = 0.0f;
        for (int k = 0; k < 64; k++) s += gw_s[si*64 + k];
        float g = sigmoidf_((s * (1.0f/64.0f)) / gate_temp[0]);
        if (!((float)deg[n] > 0.0f)) g = 1.0f;
        gate_sh[si] = g;
    }

    f32x4 acc[4][8];
    #pragma unroll
    for (int i = 0; i < 4; i++)
        #pragma unroll
        for (int j = 0; j < 8; j++)
            acc[i][j] = (f32x4){0.f,0.f,0.f,0.f};

    for (int ch = 0; ch < 8; ch++) {
        // B stage: 256 rows x 64 cols bf16 copy (L2-resident; issued before the
        // vmcnt wait on a_reg so its latency overlaps the staged-A drain)
        #pragma unroll
        for (int j = 0; j < 8; j++) {
            int row = j * 32 + (t >> 3);
            bf16x8 v = *(const bf16x8*)(Wbf + (long long)row * 512 + ch*64 + (t & 7) * 8);
            *(bf16x8*)&B_lds[row*72 + (t & 7) * 8] = v;
        }
        // A stage: convert staged registers -> bf16 -> LDS
        {
            unsigned short* dst = &A_lds[rr*72 + half*32];
            #pragma unroll
            for (int q = 0; q < 4; q++) {
                float4 v0 = a_reg[2*q];
                float4 v1 = a_reg[2*q + 1];
                bf16x8 o;
                o[0]=(short)f2bf(v0.x); o[1]=(short)f2bf(v0.y); o[2]=(short)f2bf(v0.z); o[3]=(short)f2bf(v0.w);
                o[4]=(short)f2bf(v1.x); o[5]=(short)f2bf(v1.y); o[6]=(short)f2bf(v1.z); o[7]=(short)f2bf(v1.w);
                *(bf16x8*)(dst + q*8) = o;
            }
        }
        __syncthreads();
        // prefetch next channel's A rows while MFMA runs on this channel
        if (ch < 7) ISSUE_A(ch + 1);
        #pragma unroll
        for (int ks = 0; ks < 64; ks += 32) {
            bf16x8 a[4], b[8];
            #pragma unroll
            for (int rt = 0; rt < 4; rt++)
                a[rt] = *(const bf16x8*)&A_lds[(si_w*64 + rt*16 + lr)*72 + ks + kg*8];
            #pragma unroll
            for (int ct = 0; ct < 8; ct++)
                b[ct] = *(const bf16x8*)&B_lds[(wc0 + ct*16 + lr)*72 + ks + kg*8];
            #pragma unroll
            for (int rt = 0; rt < 4; rt++)
                #pragma unroll
                for (int ct = 0; ct < 8; ct++)
                    acc[rt][ct] = __builtin_amdgcn_mfma_f32_16x16x32_bf16(a[rt], b[ct], acc[rt][ct], 0, 0, 0);
        }
        __syncthreads();
    }
    #undef ISSUE_A

    // epilogue: bias + leaky_relu + PAD mask + per-sample row sum
    #pragma unroll
    for (int ct = 0; ct < 8; ct++) {
        int d = wc0 + ct*16 + lr;
        float bd = wb[d] + bb[d];
        float pp = 0.0f;
        #pragma unroll
        for (int rt = 0; rt < 4; rt++) {
            int rbase = si_w*64 + rt*16 + kg*4;
            #pragma unroll
            for (int reg = 0; reg < 4; reg++) {
                if (rel_s[rbase + reg] != PADID) {
                    float v = acc[rt][ct][reg] + bd;
                    v = (v > 0.0f) ? v : 0.01f * v;
                    pp += v;
                }
            }
        }
        red[w][kg][ct*16 + lr] = pp;
    }
    __syncthreads();

    // final: thread t -> col t for both samples
    #pragma unroll
    for (int si = 0; si < 2; si++) {
        int wv = si*2 + (t >> 7), cl = t & 127;
        float agg = red[wv][0][cl] + red[wv][1][cl] + red[wv][2][cl] + red[wv][3][cl];
        const int *conn, *deg, *ids; int n, ids_off, row, col;
        ne_decode(bid*2 + si, q_l1,q_deg_l,q_r1,q_deg_r,s_l1,s_deg_l,s_r1,s_deg_r,
                  query, support, conn, deg, ids, n, ids_off, row, col);
        float degf = fmaxf((float)deg[n], 1.0f);
        agg /= degf;
        int id = ids[n*2 + ids_off];
        float o = ftanh(emb[(long long)id * 256 + t] + gate_sh[si] * agg);
        vec_bf[(long long)row * 512 + col + t] = f2bf(o);
    }
}

// ---------------------------------------------------------------------------
// Generic bf16 MFMA GEMM (support encoder): C = act(A.B^T + bias + add)
// 128x128 tile, BK=64, LDS stride 72.
// ---------------------------------------------------------------------------
template<int HB, int HADD, int RELU, int WF, int WB>
__global__ __launch_bounds__(256) void mfma_gemm(
    const unsigned short* __restrict__ A, const unsigned short* __restrict__ B,
    const float* __restrict__ bias, const unsigned short* __restrict__ addbf,
    float* __restrict__ Cf, unsigned short* __restrict__ Cb, int N, int M, int K)
{
    __shared__ unsigned short A_lds[128 * 72];
    __shared__ unsigned short B_lds[128 * 72];
    const int t = threadIdx.x;
    const int bm0 = blockIdx.x * 128, bn0 = blockIdx.y * 128;
    const int lane = t & 63, w = t >> 6, wn = w >> 1, wm = w & 1;
    const int lr = lane & 15, kg = lane >> 4;

    f32x4 acc[4][4];
    #pragma unroll
    for (int i = 0; i < 4; i++)
        #pragma unroll
        for (int j = 0; j < 4; j++)
            acc[i][j] = (f32x4){0.f,0.f,0.f,0.f};

    const int r = t >> 1, half = t & 1;
    const unsigned short* Ap = A + (size_t)(bn0 + r) * K + half * 32;
    const unsigned short* Bp = B + (size_t)(bm0 + r) * K + half * 32;
    unsigned short* Aw = &A_lds[r*72 + half*32];
    unsigned short* Bw = &B_lds[r*72 + half*32];

    for (int c0 = 0; c0 < K; c0 += 64) {
        #pragma unroll
        for (int q = 0; q < 4; q++) {
            *(bf16x8*)(Aw + q*8) = *(const bf16x8*)(Ap + c0 + q*8);
            *(bf16x8*)(Bw + q*8) = *(const bf16x8*)(Bp + c0 + q*8);
        }
        __syncthreads();
        #pragma unroll
        for (int ks = 0; ks < 64; ks += 32) {
            bf16x8 a[4], b[4];
            #pragma unroll
            for (int rt = 0; rt < 4; rt++)
                a[rt] = *(const bf16x8*)&A_lds[(wn*64 + rt*16 + lr)*72 + ks + kg*8];
            #pragma unroll
            for (int ct = 0; ct < 4; ct++)
                b[ct] = *(const bf16x8*)&B_lds[(wm*64 + ct*16 + lr)*72 + ks + kg*8];
            #pragma unroll
            for (int rt = 0; rt < 4; rt++)
                #pragma unroll
                for (int ct = 0; ct < 4; ct++)
                    acc[rt][ct] = __builtin_amdgcn_mfma_f32_16x16x32_bf16(a[rt], b[ct], acc[rt][ct], 0, 0, 0);
        }
        __syncthreads();
    }

    float bsum[4];
    #pragma unroll
    for (int ct = 0; ct < 4; ct++)
        bsum[ct] = HB ? bias[bm0 + wm*64 + ct*16 + lr] : 0.0f;
    #pragma unroll
    for (int rt = 0; rt < 4; rt++) {
        #pragma unroll
        for (int reg = 0; reg < 4; reg++) {
            int n = bn0 + wn*64 + rt*16 + kg*4 + reg;
            if (n < N) {
                size_t rowb = (size_t)n * M + bm0 + wm*64;
                #pragma unroll
                for (int ct = 0; ct < 4; ct++) {
                    size_t idx = rowb + ct*16 + lr;
                    float v = acc[rt][ct][reg] + bsum[ct];
                    if (HADD) v += bf2f(addbf[idx]);
                    if (RELU) v = fmaxf(v, 0.0f);
                    if (WF) Cf[idx] = v;
                    if (WB) Cb[idx] = f2bf(v);
                }
            }
        }
    }
}

// ---------------------------------------------------------------------------
// LSTM GEMM with fused elementwise. Gate-interleaved layout (perm m').
// FIRST: gates = A.B^T + bias0_p; writes G0_bf, c=si*tanh(g), h.
// else:  gates = A.B^T + svec_p + bf(G0); c = sf*c + si*tanh(g); h.
// N=2048, M=4096, K=512, grid (32,16).
// ---------------------------------------------------------------------------
template<int FIRST>
__global__ __launch_bounds__(256, 2) void lstm_gemm(
    const unsigned short* __restrict__ A, const unsigned short* __restrict__ B,
    const float* __restrict__ biasv, unsigned short* __restrict__ G0,
    float* __restrict__ c_st, const float* __restrict__ qenc,
    unsigned short* __restrict__ h_bf)
{
    __shared__ unsigned short A_lds[128 * 72];
    __shared__ unsigned short B_lds[128 * 72];
    const int t = threadIdx.x;
    const int bm0 = blockIdx.x * 128, bn0 = blockIdx.y * 128;
    const int lane = t & 63, w = t >> 6, wn = w >> 1, wm = w & 1;
    const int lr = lane & 15, kg = lane >> 4;

    f32x4 acc[4][4];
    #pragma unroll
    for (int i = 0; i < 4; i++)
        #pragma unroll
        for (int j = 0; j < 4; j++)
            acc[i][j] = (f32x4){0.f,0.f,0.f,0.f};

    const int r = t >> 1, half = t & 1;
    const unsigned short* Ap = A + (size_t)(bn0 + r) * 512 + half * 32;
    const unsigned short* Bp = B + (size_t)(bm0 + r) * 512 + half * 32;
    unsigned short* Aw = &A_lds[r*72 + half*32];
    unsigned short* Bw = &B_lds[r*72 + half*32];

    for (int c0 = 0; c0 < 512; c0 += 64) {
        #pragma unroll
        for (int q = 0; q < 4; q++) {
            *(bf16x8*)(Aw + q*8) = *(const bf16x8*)(Ap + c0 + q*8);
            *(bf16x8*)(Bw + q*8) = *(const bf16x8*)(Bp + c0 + q*8);
        }
        __syncthreads();
        #pragma unroll
        for (int ks = 0; ks < 64; ks += 32) {
            bf16x8 a[4], b[4];
            #pragma unroll
            for (int rt = 0; rt < 4; rt++)
                a[rt] = *(const bf16x8*)&A_lds[(wn*64 + rt*16 + lr)*72 + ks + kg*8];
            #pragma unroll
            for (int ct = 0; ct < 4; ct++)
                b[ct] = *(const bf16x8*)&B_lds[(wm*64 + ct*16 + lr)*72 + ks + kg*8];
            #pragma unroll
            for (int rt = 0; rt < 4; rt++)
                #pragma unroll
                for (int ct = 0; ct < 4; ct++)
                    acc[rt][ct] = __builtin_amdgcn_mfma_f32_16x16x32_bf16(a[rt], b[ct], acc[rt][ct], 0, 0, 0);
        }
        __syncthreads();
    }

    const int g0col = (bm0 + wm*64) >> 6;     // 0..63
    const int j = g0col*16 + lr;              // 0..1023
    float e[4];
    #pragma unroll
    for (int ct = 0; ct < 4; ct++)
        e[ct] = biasv[bm0 + wm*64 + ct*16 + lr];

    #pragma unroll
    for (int rt = 0; rt < 4; rt++) {
        #pragma unroll
        for (int reg = 0; reg < 4; reg++) {
            int n = bn0 + wn*64 + rt*16 + kg*4 + reg;
            size_t gbase = (size_t)n * 4096 + bm0 + wm*64;
            float gi = acc[rt][0][reg] + e[0];
            float gf = acc[rt][1][reg] + e[1];
            float gg = acc[rt][2][reg] + e[2];
            float go = acc[rt][3][reg] + e[3];
            if (FIRST) {
                G0[gbase + 0*16 + lr] = f2bf(gi);
                G0[gbase + 1*16 + lr] = f2bf(gf);
                G0[gbase + 2*16 + lr] = f2bf(gg);
                G0[gbase + 3*16 + lr] = f2bf(go);
            } else {
                gi += bf2f(G0[gbase + 0*16 + lr]);
                gf += bf2f(G0[gbase + 1*16 + lr]);
                gg += bf2f(G0[gbase + 2*16 + lr]);
                go += bf2f(G0[gbase + 3*16 + lr]);
            }
            size_t cidx = (size_t)n * 1024 + j;
            float cprev = FIRST ? 0.0f : c_st[cidx];
            float cv = sigmoidf_(gf) * cprev + sigmoidf_(gi) * ftanh(gg);
            c_st[cidx] = cv;
            float hn = sigmoidf_(go) * ftanh(cv);
            if (j < 512)
                h_bf[(size_t)n * 512 + j] = f2bf(qenc[(size_t)n * 512 + j] + hn);
        }
    }
}

// ---------------------------------------------------------------------------
// LayerNorm ddof=1, row length 512; fp32 + bf16 outputs
// ---------------------------------------------------------------------------
__global__ __launch_bounds__(256) void ln_kernel(
    const float* __restrict__ z, const float* __restrict__ a,
    const float* __restrict__ b, float* __restrict__ o,
    unsigned short* __restrict__ ob)
{
    __shared__ float red[256];
    int n = blockIdx.x, t = threadIdx.x;
    const float* zp = z + (long long)n * 512;
    float2 v = *(const float2*)(zp + t*2);
    red[t] = v.x + v.y;
    __syncthreads();
    for (int off = 128; off > 0; off >>= 1) {
        if (t < off) red[t] += red[t+off];
        __syncthreads();
    }
    float mu = red[0] * (1.0f/512.0f);
    __syncthreads();
    float d0 = v.x - mu, d1 = v.y - mu;
    red[t] = d0*d0 + d1*d1;
    __syncthreads();
    for (int off = 128; off > 0; off >>= 1) {
        if (t < off) red[t] += red[t+off];
        __syncthreads();
    }
    float var = red[0] * (1.0f/511.0f);
    float inv = 1.0f / (sqrtf(var) + 1e-3f);
    float r0 = d0 * inv * a[t*2]   + b[t*2];
    float r1 = d1 * inv * a[t*2+1] + b[t*2+1];
    float* op = o + (long long)n * 512;
    op[t*2] = r0; op[t*2+1] = r1;
    unsigned short* obp = ob + (long long)n * 512;
    obp[t*2] = f2bf(r0); obp[t*2+1] = f2bf(r1);
}

__global__ __launch_bounds__(256) void mean5_kernel(
    const float* __restrict__ se, float* __restrict__ sg)
{
    int d = blockIdx.x * 256 + threadIdx.x;
    if (d < 512) {
        float s = 0.0f;
        #pragma unroll
        for (int f = 0; f < 5; f++) s += se[f*512 + d];
        sg[d] = s * 0.2f;
    }
}

// svec_p[m'] = sum_k s_g[k] * W_hh[orig(m')][512+k]
__global__ __launch_bounds__(256) void svecg_kernel(
    const float* __restrict__ sg, const float* __restrict__ Whh,
    float* __restrict__ outv)
{
    __shared__ float sgl[512];
    int t = threadIdx.x;
    sgl[t] = sg[t]; sgl[256+t] = sg[256+t];
    __syncthreads();
    int mp = blockIdx.x * 256 + t;
    int orig = perm_orig(mp);
    const float* wp = Whh + (long long)orig * 1024 + 512;
    float s = 0.0f;
    for (int k = 0; k < 512; k += 4) {
        float4 wv = *(const float4*)(wp + k);
        s += sgl[k]*wv.x + sgl[k+1]*wv.y + sgl[k+2]*wv.z + sgl[k+3]*wv.w;
    }
    outv[mp] = s;
}

// out[n] = dot(h_bf[n], s_g)
__global__ __launch_bounds__(256) void dot_kernel(
    const unsigned short* __restrict__ h_bf, const float* __restrict__ sg,
    float* __restrict__ out)
{
    int w = threadIdx.x >> 6, lane = threadIdx.x & 63;
    int n = blockIdx.x * 4 + w;
    bf16x8 hv = *(const bf16x8*)(h_bf + (long long)n * 512 + lane * 8);
    const float* sp = sg + lane * 8;
    float4 b0 = *(const float4*)sp, b1 = *(const float4*)(sp+4);
    float bs[8] = {b0.x,b0.y,b0.z,b0.w,b1.x,b1.y,b1.z,b1.w};
    float p = 0.0f;
    #pragma unroll
    for (int q = 0; q < 8; q++) p += bf2f((unsigned short)hv[q]) * bs[q];
    #pragma unroll
    for (int off = 32; off > 0; off >>= 1) p += __shfl_down(p, off);
    if (lane == 0) out[n] = p;
}

extern "C" void kernel_launch(void* const* d_in, const int* in_sizes, int n_in,
                              void* d_out, int out_size, void* d_ws, size_t ws_size,
                              hipStream_t stream)
{
    (void)in_sizes; (void)n_in; (void)out_size; (void)ws_size;
    const float* emb       = (const float*)d_in[0];
    const float* gcn_W     = (const float*)d_in[1];
    const float* gcn_wb    = (const float*)d_in[2];
    const float* gcn_b     = (const float*)d_in[3];
    const float* gate_w    = (const float*)d_in[4];
    const float* gate_temp = (const float*)d_in[5];
    const float* p1_W      = (const float*)d_in[6];
    const float* p1_b      = (const float*)d_in[7];
    const float* p2_W      = (const float*)d_in[8];
    const float* p2_b      = (const float*)d_in[9];
    const float* ln_a      = (const float*)d_in[10];
    const float* ln_b      = (const float*)d_in[11];
    const float* W_ih      = (const float*)d_in[12];
    const float* W_hh      = (const float*)d_in[13];
    const float* b_ih      = (const float*)d_in[14];
    const float* b_hh      = (const float*)d_in[15];
    const int*   query     = (const int*)d_in[16];
    const int*   support   = (const int*)d_in[17];
    const int*   q_l1      = (const int*)d_in[18];
    const int*   q_deg_l   = (const int*)d_in[19];
    const int*   q_r1      = (const int*)d_in[20];
    const int*   q_deg_r   = (const int*)d_in[21];
    const int*   s_l1      = (const int*)d_in[22];
    const int*   s_deg_l   = (const int*)d_in[23];
    const int*   s_r1      = (const int*)d_in[24];
    const int*   s_deg_r   = (const int*)d_in[25];
    float* out = (float*)d_out;
    typedef unsigned short us;

    char* wp_ = (char*)d_ws;
    auto take = [&](size_t bytes) { void* p = wp_; wp_ += (bytes + 255) & ~(size_t)255; return p; };
    us*    vec_bf  = (us*)   take((size_t)2176*512*2);   // rows 0..2047 q, 2048..2052 s
    us*    h1_bf   = (us*)   take((size_t)2176*1024*2);
    float* z_buf   = (float*)take((size_t)2176*512*4);
    float* enc_f   = (float*)take((size_t)2176*512*4);
    us*    enc_bf  = (us*)   take((size_t)2176*512*2);
    float* s_g     = (float*)take(512*4);
    float* bias0_p = (float*)take(4096*4);
    float* svec_p  = (float*)take(4096*4);
    float* c_st    = (float*)take((size_t)2048*1024*4);
    us*    h_bf    = (us*)   take((size_t)2048*512*2);
    us*    wgcn    = (us*)   take((size_t)256*512*2);
    us*    p1w     = (us*)   take((size_t)1024*512*2);
    us*    p2w     = (us*)   take((size_t)512*1024*2);
    us*    wih_p   = (us*)   take((size_t)4096*512*2);
    us*    whh_p   = (us*)   take((size_t)4096*512*2);
    us*    G0_bf   = (us*)   take((size_t)2048*4096*2);

    // 1) weights -> bf16 (+ gate-interleave permutation for LSTM)
    preconvert<<<5252, 256, 0, stream>>>(gcn_W, p1_W, p2_W, W_ih, W_hh, b_ih, b_hh,
        wgcn, p1w, p2w, wih_p, whh_p, bias0_p);

    // 2) neighbor encoders (2 samples/block)
    ne_fused<<<2053, 256, 0, stream>>>(emb, wgcn, gcn_wb, gcn_b, gate_w, gate_temp,
        q_l1, q_deg_l, q_r1, q_deg_r, s_l1, s_deg_l, s_r1, s_deg_r,
        query, support, vec_bf);

    // 3) support encoder over q+s rows (N=2053): p1 relu -> p2 +resid -> LN
    mfma_gemm<1,0,1,0,1><<<dim3(8,17), 256, 0, stream>>>(vec_bf, p1w, p1_b, nullptr, nullptr, h1_bf, 2053, 1024, 512);
    mfma_gemm<1,1,0,1,0><<<dim3(4,17), 256, 0, stream>>>(h1_bf, p2w, p2_b, vec_bf, z_buf, nullptr, 2053, 512, 1024);
    ln_kernel<<<2053, 256, 0, stream>>>(z_buf, ln_a, ln_b, enc_f, enc_bf);
    mean5_kernel<<<2, 256, 0, stream>>>(enc_f + (size_t)2048*512, s_g);
    svecg_kernel<<<16, 256, 0, stream>>>(s_g, W_hh, svec_p);

    // 4) LSTM: G0 gemm + step-1 ew fused, then 3 fused steps
    lstm_gemm<1><<<dim3(32,16), 256, 0, stream>>>(enc_bf, wih_p, bias0_p, G0_bf, c_st, enc_f, h_bf);
    for (int s2 = 0; s2 < 3; s2++)
        lstm_gemm<0><<<dim3(32,16), 256, 0, stream>>>(h_bf, whh_p, svec_p, G0_bf, c_st, enc_f, h_bf);

    // 5) final scores
    dot_kernel<<<512, 256, 0, stream>>>(h_bf, s_g, out);
}

// Round 2
// 846.391 us; speedup vs baseline: 1.0567x; 1.0495x over previous
//
#include <hip/hip_runtime.h>
#include <math.h>

#define PADID 400000

typedef __attribute__((ext_vector_type(8))) short bf16x8;
typedef __attribute__((ext_vector_type(4))) float f32x4;

__device__ __forceinline__ float sigmoidf_(float x){ return 1.0f/(1.0f+__expf(-x)); }
__device__ __forceinline__ float ftanh(float x){ return 1.0f - 2.0f/(__expf(2.0f*x)+1.0f); }

__device__ __forceinline__ unsigned short f2bf(float f){
    unsigned u = __float_as_uint(f);
    u += 0x7FFFu + ((u >> 16) & 1u);
    return (unsigned short)(u >> 16);
}
__device__ __forceinline__ float bf2f(unsigned short s){
    return __uint_as_float(((unsigned)s) << 16);
}

// gate-interleaved permutation: m' -> original gate-major row
__device__ __forceinline__ int perm_orig(int mp){
    int gate = (mp >> 4) & 3;
    int j = (mp >> 6) * 16 + (mp & 15);
    return gate * 1024 + j;
}

// ---------------------------------------------------------------------------
// Weight preconversion fp32 -> bf16 + permutations (one pass).
// ---------------------------------------------------------------------------
__global__ __launch_bounds__(256) void preconvert(
    const float* __restrict__ gcnW, const float* __restrict__ p1W,
    const float* __restrict__ p2W, const float* __restrict__ Wih,
    const float* __restrict__ Whh, const float* __restrict__ b_ih,
    const float* __restrict__ b_hh,
    unsigned short* __restrict__ wgcn, unsigned short* __restrict__ p1w,
    unsigned short* __restrict__ p2w, unsigned short* __restrict__ wih_p,
    unsigned short* __restrict__ whh_p, float* __restrict__ bias0_p)
{
    long long i = ((long long)blockIdx.x * 256 + threadIdx.x) * 4;
    float4 v;
    if (i < 131072LL) {
        v = *(const float4*)(gcnW + i);
        unsigned a0 = f2bf(v.x) | ((unsigned)f2bf(v.y) << 16);
        unsigned a1 = f2bf(v.z) | ((unsigned)f2bf(v.w) << 16);
        *(uint2*)(wgcn + i) = make_uint2(a0, a1);
    } else if (i < 655360LL) {
        long long off = i - 131072LL;
        v = *(const float4*)(p1W + off);
        unsigned a0 = f2bf(v.x) | ((unsigned)f2bf(v.y) << 16);
        unsigned a1 = f2bf(v.z) | ((unsigned)f2bf(v.w) << 16);
        *(uint2*)(p1w + off) = make_uint2(a0, a1);
    } else if (i < 1179648LL) {
        long long off = i - 655360LL;
        v = *(const float4*)(p2W + off);
        unsigned a0 = f2bf(v.x) | ((unsigned)f2bf(v.y) << 16);
        unsigned a1 = f2bf(v.z) | ((unsigned)f2bf(v.w) << 16);
        *(uint2*)(p2w + off) = make_uint2(a0, a1);
    } else if (i < 3276800LL) {
        long long off = i - 1179648LL;
        int mp = (int)(off >> 9), col = (int)(off & 511);
        int orig = perm_orig(mp);
        v = *(const float4*)(Wih + (long long)orig * 512 + col);
        unsigned a0 = f2bf(v.x) | ((unsigned)f2bf(v.y) << 16);
        unsigned a1 = f2bf(v.z) | ((unsigned)f2bf(v.w) << 16);
        *(uint2*)(wih_p + off) = make_uint2(a0, a1);
    } else if (i < 5373952LL) {
        long long off = i - 3276800LL;
        int mp = (int)(off >> 9), col = (int)(off & 511);
        int orig = perm_orig(mp);
        v = *(const float4*)(Whh + (long long)orig * 1024 + col);
        unsigned a0 = f2bf(v.x) | ((unsigned)f2bf(v.y) << 16);
        unsigned a1 = f2bf(v.z) | ((unsigned)f2bf(v.w) << 16);
        *(uint2*)(whh_p + off) = make_uint2(a0, a1);
    } else if (i < 5378048LL) {
        long long off = i - 5373952LL;
        #pragma unroll
        for (int q = 0; q < 4; q++) {
            int mp = (int)off + q;
            int orig = perm_orig(mp);
            bias0_p[mp] = b_ih[orig] + b_hh[orig];
        }
    }
}

// ---------------------------------------------------------------------------
// Neighbor encoder, 1 sample/block. A = gathered emb rows (64 x 512 bf16),
// B = gcn_W bf16 (256 x 512). 4 waves, each computes all 64 rows x 64 cols.
// LDS ~47 KB -> 3 blocks/CU; acc[4][4] (64 VGPR) -> no spill risk.
// Rowsum reduction via in-wave kg-butterfly (no LDS red array).
// ---------------------------------------------------------------------------
__device__ __forceinline__ void ne_decode(int s,
    const int* q_l1, const int* q_deg_l, const int* q_r1, const int* q_deg_r,
    const int* s_l1, const int* s_deg_l, const int* s_r1, const int* s_deg_r,
    const int* query, const int* support,
    const int*& conn, const int*& deg, const int*& ids, int& n, int& ids_off, int& row, int& col)
{
    if (s < 2048)      { conn = q_l1; deg = q_deg_l; ids = query;   n = s;      ids_off = 0; row = s;        col = 0;   }
    else if (s < 4096) { conn = q_r1; deg = q_deg_r; ids = query;   n = s-2048; ids_off = 1; row = s-2048;   col = 256; }
    else if (s < 4101) { conn = s_l1; deg = s_deg_l; ids = support; n = s-4096; ids_off = 0; row = 2048+n;   col = 0;   }
    else               { conn = s_r1; deg = s_deg_r; ids = support; n = s-4101; ids_off = 1; row = 2048+n;   col = 256; }
}

__global__ __launch_bounds__(256, 3) void ne_fused(
    const float* __restrict__ emb, const unsigned short* __restrict__ Wbf,
    const float* __restrict__ wb, const float* __restrict__ bb,
    const float* __restrict__ gate_w, const float* __restrict__ gate_temp,
    const int* __restrict__ q_l1, const int* __restrict__ q_deg_l,
    const int* __restrict__ q_r1, const int* __restrict__ q_deg_r,
    const int* __restrict__ s_l1, const int* __restrict__ s_deg_l,
    const int* __restrict__ s_r1, const int* __restrict__ s_deg_r,
    const int* __restrict__ query, const int* __restrict__ support,
    unsigned short* __restrict__ vec_bf)
{
    __shared__ int   rel_s[64];
    __shared__ int   ent_s[64];
    __shared__ unsigned short A_lds[64 * 72];
    __shared__ unsigned short B_lds[256 * 72];
    __shared__ float gate_sh;

    const int t = threadIdx.x;
    const int lane = t & 63, w = t >> 6, lr = lane & 15, kg = lane >> 4;
    const int wc0 = w * 64;             // col base of this wave (0..192)

    // decode this block's sample
    const int *conn, *deg, *ids; int n, ids_off, row, col;
    ne_decode(blockIdx.x, q_l1,q_deg_l,q_r1,q_deg_r,s_l1,s_deg_l,s_r1,s_deg_r,
              query, support, conn, deg, ids, n, ids_off, row, col);

    // load conn (64 neighbors x {rel, ent})
    if (t < 128) {
        int v = conn[n*128 + t];
        if (t & 1) ent_s[t>>1] = v; else rel_s[t>>1] = v;
    }
    __syncthreads();

    const int arow = t >> 2, aq = t & 3;  // A-stage: row 0..63, quarter 0..3

    // ---- pipelined A-gather staging registers (16 floats / thread) ----
    float4 a_reg[4];
    #define ISSUE_A(ch_) { \
        const int side_ = ((ch_) >= 4); \
        const int cg0_ = ((ch_) & 3) * 64; \
        int rowid_ = side_ ? ent_s[arow] : rel_s[arow]; \
        const float* src_ = emb + (long long)rowid_ * 256 + cg0_ + aq * 16; \
        _Pragma("unroll") \
        for (int q_ = 0; q_ < 4; q_++) a_reg[q_] = *(const float4*)(src_ + q_*4); \
    }

    ISSUE_A(0);

    // gate: wave 0 gathers gate_w and reduces in-wave
    if (t < 64) {
        int r = rel_s[t];
        float gwv = gate_w[(r == PADID) ? 0 : r];
        #pragma unroll
        for (int off = 32; off > 0; off >>= 1) gwv += __shfl_down(gwv, off);
        if (t == 0) {
            float g = sigmoidf_((gwv * (1.0f/64.0f)) / gate_temp[0]);
            if (!((float)deg[n] > 0.0f)) g = 1.0f;
            gate_sh = g;
        }
    }

    f32x4 acc[4][4];
    #pragma unroll
    for (int i = 0; i < 4; i++)
        #pragma unroll
        for (int j = 0; j < 4; j++)
            acc[i][j] = (f32x4){0.f,0.f,0.f,0.f};

    for (int ch = 0; ch < 8; ch++) {
        // B stage: 256 rows x 64 cols bf16 copy (L2-resident)
        #pragma unroll
        for (int j = 0; j < 8; j++) {
            int brow = j * 32 + (t >> 3);
            bf16x8 v = *(const bf16x8*)(Wbf + (long long)brow * 512 + ch*64 + (t & 7) * 8);
            *(bf16x8*)&B_lds[brow*72 + (t & 7) * 8] = v;
        }
        // A stage: staged registers -> bf16 -> LDS (16 cols per thread)
        {
            unsigned short* dst = &A_lds[arow*72 + aq*16];
            bf16x8 o0, o1;
            o0[0]=(short)f2bf(a_reg[0].x); o0[1]=(short)f2bf(a_reg[0].y);
            o0[2]=(short)f2bf(a_reg[0].z); o0[3]=(short)f2bf(a_reg[0].w);
            o0[4]=(short)f2bf(a_reg[1].x); o0[5]=(short)f2bf(a_reg[1].y);
            o0[6]=(short)f2bf(a_reg[1].z); o0[7]=(short)f2bf(a_reg[1].w);
            o1[0]=(short)f2bf(a_reg[2].x); o1[1]=(short)f2bf(a_reg[2].y);
            o1[2]=(short)f2bf(a_reg[2].z); o1[3]=(short)f2bf(a_reg[2].w);
            o1[4]=(short)f2bf(a_reg[3].x); o1[5]=(short)f2bf(a_reg[3].y);
            o1[6]=(short)f2bf(a_reg[3].z); o1[7]=(short)f2bf(a_reg[3].w);
            *(bf16x8*)(dst)     = o0;
            *(bf16x8*)(dst + 8) = o1;
        }
        __syncthreads();
        // prefetch next channel's A rows while MFMA runs on this channel
        if (ch < 7) ISSUE_A(ch + 1);
        #pragma unroll
        for (int ks = 0; ks < 64; ks += 32) {
            bf16x8 a[4], b[4];
            #pragma unroll
            for (int rt = 0; rt < 4; rt++)
                a[rt] = *(const bf16x8*)&A_lds[(rt*16 + lr)*72 + ks + kg*8];
            #pragma unroll
            for (int ct = 0; ct < 4; ct++)
                b[ct] = *(const bf16x8*)&B_lds[(wc0 + ct*16 + lr)*72 + ks + kg*8];
            #pragma unroll
            for (int rt = 0; rt < 4; rt++)
                #pragma unroll
                for (int ct = 0; ct < 4; ct++)
                    acc[rt][ct] = __builtin_amdgcn_mfma_f32_16x16x32_bf16(a[rt], b[ct], acc[rt][ct], 0, 0, 0);
        }
        __syncthreads();
    }
    #undef ISSUE_A

    // epilogue: bias + leaky_relu + PAD mask + rowsum, kg-butterfly reduce
    float outv0, outv1, outv2, outv3;
    #pragma unroll
    for (int ct = 0; ct < 4; ct++) {
        int d = wc0 + ct*16 + lr;
        float bd = wb[d] + bb[d];
        float pp = 0.0f;
        #pragma unroll
        for (int rt = 0; rt < 4; rt++) {
            int rbase = rt*16 + kg*4;
            #pragma unroll
            for (int reg = 0; reg < 4; reg++) {
                if (rel_s[rbase + reg] != PADID) {
                    float v = acc[rt][ct][reg] + bd;
                    v = (v > 0.0f) ? v : 0.01f * v;
                    pp += v;
                }
            }
        }
        pp += __shfl_xor(pp, 16);
        pp += __shfl_xor(pp, 32);
        if (ct == 0) outv0 = pp; else if (ct == 1) outv1 = pp;
        else if (ct == 2) outv2 = pp; else outv3 = pp;
    }
    // lane writes col d = wc0 + kg*16 + lr  (its ct == kg value)
    float agg = (kg == 0) ? outv0 : (kg == 1) ? outv1 : (kg == 2) ? outv2 : outv3;
    int dcol = wc0 + kg*16 + lr;
    float degf = fmaxf((float)deg[n], 1.0f);
    agg /= degf;
    int id = ids[n*2 + ids_off];
    float o = ftanh(emb[(long long)id * 256 + dcol] + gate_sh * agg);
    vec_bf[(long long)row * 512 + col + dcol] = f2bf(o);
}

// ---------------------------------------------------------------------------
// Generic bf16 MFMA GEMM (support encoder): C = act(A.B^T + bias + add)
// 128x128 tile, BK=64, LDS stride 72.
// ---------------------------------------------------------------------------
template<int HB, int HADD, int RELU, int WF, int WB>
__global__ __launch_bounds__(256) void mfma_gemm(
    const unsigned short* __restrict__ A, const unsigned short* __restrict__ B,
    const float* __restrict__ bias, const unsigned short* __restrict__ addbf,
    float* __restrict__ Cf, unsigned short* __restrict__ Cb, int N, int M, int K)
{
    __shared__ unsigned short A_lds[128 * 72];
    __shared__ unsigned short B_lds[128 * 72];
    const int t = threadIdx.x;
    const int bm0 = blockIdx.x * 128, bn0 = blockIdx.y * 128;
    const int lane = t & 63, w = t >> 6, wn = w >> 1, wm = w & 1;
    const int lr = lane & 15, kg = lane >> 4;

    f32x4 acc[4][4];
    #pragma unroll
    for (int i = 0; i < 4; i++)
        #pragma unroll
        for (int j = 0; j < 4; j++)
            acc[i][j] = (f32x4){0.f,0.f,0.f,0.f};

    const int r = t >> 1, half = t & 1;
    const unsigned short* Ap = A + (size_t)(bn0 + r) * K + half * 32;
    const unsigned short* Bp = B + (size_t)(bm0 + r) * K + half * 32;
    unsigned short* Aw = &A_lds[r*72 + half*32];
    unsigned short* Bw = &B_lds[r*72 + half*32];

    for (int c0 = 0; c0 < K; c0 += 64) {
        #pragma unroll
        for (int q = 0; q < 4; q++) {
            *(bf16x8*)(Aw + q*8) = *(const bf16x8*)(Ap + c0 + q*8);
            *(bf16x8*)(Bw + q*8) = *(const bf16x8*)(Bp + c0 + q*8);
        }
        __syncthreads();
        #pragma unroll
        for (int ks = 0; ks < 64; ks += 32) {
            bf16x8 a[4], b[4];
            #pragma unroll
            for (int rt = 0; rt < 4; rt++)
                a[rt] = *(const bf16x8*)&A_lds[(wn*64 + rt*16 + lr)*72 + ks + kg*8];
            #pragma unroll
            for (int ct = 0; ct < 4; ct++)
                b[ct] = *(const bf16x8*)&B_lds[(wm*64 + ct*16 + lr)*72 + ks + kg*8];
            #pragma unroll
            for (int rt = 0; rt < 4; rt++)
                #pragma unroll
                for (int ct = 0; ct < 4; ct++)
                    acc[rt][ct] = __builtin_amdgcn_mfma_f32_16x16x32_bf16(a[rt], b[ct], acc[rt][ct], 0, 0, 0);
        }
        __syncthreads();
    }

    float bsum[4];
    #pragma unroll
    for (int ct = 0; ct < 4; ct++)
        bsum[ct] = HB ? bias[bm0 + wm*64 + ct*16 + lr] : 0.0f;
    #pragma unroll
    for (int rt = 0; rt < 4; rt++) {
        #pragma unroll
        for (int reg = 0; reg < 4; reg++) {
            int n = bn0 + wn*64 + rt*16 + kg*4 + reg;
            if (n < N) {
                size_t rowb = (size_t)n * M + bm0 + wm*64;
                #pragma unroll
                for (int ct = 0; ct < 4; ct++) {
                    size_t idx = rowb + ct*16 + lr;
                    float v = acc[rt][ct][reg] + bsum[ct];
                    if (HADD) v += bf2f(addbf[idx]);
                    if (RELU) v = fmaxf(v, 0.0f);
                    if (WF) Cf[idx] = v;
                    if (WB) Cb[idx] = f2bf(v);
                }
            }
        }
    }
}

// ---------------------------------------------------------------------------
// LSTM GEMM with fused elementwise. Gate-interleaved layout (perm m').
// MODE 1 (FIRST): gates = A.B^T + bias0_p; writes G0_bf, c=si*tanh(g), h.
// MODE 0 (MID):   gates = A.B^T + svec_p + bf(G0); c = sf*c + si*tanh(g); h.
// MODE 2 (LAST):  like MID but only gate cols m'<2048 (j<512) are needed
//                 (grid.x=16) and c is not stored (never consumed again).
// ---------------------------------------------------------------------------
template<int MODE>
__global__ __launch_bounds__(256, 2) void lstm_gemm(
    const unsigned short* __restrict__ A, const unsigned short* __restrict__ B,
    const float* __restrict__ biasv, unsigned short* __restrict__ G0,
    float* __restrict__ c_st, const float* __restrict__ qenc,
    unsigned short* __restrict__ h_bf)
{
    __shared__ unsigned short A_lds[128 * 72];
    __shared__ unsigned short B_lds[128 * 72];
    const int t = threadIdx.x;
    const int bm0 = blockIdx.x * 128, bn0 = blockIdx.y * 128;
    const int lane = t & 63, w = t >> 6, wn = w >> 1, wm = w & 1;
    const int lr = lane & 15, kg = lane >> 4;

    f32x4 acc[4][4];
    #pragma unroll
    for (int i = 0; i < 4; i++)
        #pragma unroll
        for (int j = 0; j < 4; j++)
            acc[i][j] = (f32x4){0.f,0.f,0.f,0.f};

    const int r = t >> 1, half = t & 1;
    const unsigned short* Ap = A + (size_t)(bn0 + r) * 512 + half * 32;
    const unsigned short* Bp = B + (size_t)(bm0 + r) * 512 + half * 32;
    unsigned short* Aw = &A_lds[r*72 + half*32];
    unsigned short* Bw = &B_lds[r*72 + half*32];

    for (int c0 = 0; c0 < 512; c0 += 64) {
        #pragma unroll
        for (int q = 0; q < 4; q++) {
            *(bf16x8*)(Aw + q*8) = *(const bf16x8*)(Ap + c0 + q*8);
            *(bf16x8*)(Bw + q*8) = *(const bf16x8*)(Bp + c0 + q*8);
        }
        __syncthreads();
        #pragma unroll
        for (int ks = 0; ks < 64; ks += 32) {
            bf16x8 a[4], b[4];
            #pragma unroll
            for (int rt = 0; rt < 4; rt++)
                a[rt] = *(const bf16x8*)&A_lds[(wn*64 + rt*16 + lr)*72 + ks + kg*8];
            #pragma unroll
            for (int ct = 0; ct < 4; ct++)
                b[ct] = *(const bf16x8*)&B_lds[(wm*64 + ct*16 + lr)*72 + ks + kg*8];
            #pragma unroll
            for (int rt = 0; rt < 4; rt++)
                #pragma unroll
                for (int ct = 0; ct < 4; ct++)
                    acc[rt][ct] = __builtin_amdgcn_mfma_f32_16x16x32_bf16(a[rt], b[ct], acc[rt][ct], 0, 0, 0);
        }
        __syncthreads();
    }

    const int g0col = (bm0 + wm*64) >> 6;     // 0..63
    const int j = g0col*16 + lr;              // 0..1023
    float e[4];
    #pragma unroll
    for (int ct = 0; ct < 4; ct++)
        e[ct] = biasv[bm0 + wm*64 + ct*16 + lr];

    #pragma unroll
    for (int rt = 0; rt < 4; rt++) {
        #pragma unroll
        for (int reg = 0; reg < 4; reg++) {
            int n = bn0 + wn*64 + rt*16 + kg*4 + reg;
            size_t gbase = (size_t)n * 4096 + bm0 + wm*64;
            float gi = acc[rt][0][reg] + e[0];
            float gf = acc[rt][1][reg] + e[1];
            float gg = acc[rt][2][reg] + e[2];
            float go = acc[rt][3][reg] + e[3];
            if (MODE == 1) {
                G0[gbase + 0*16 + lr] = f2bf(gi);
                G0[gbase + 1*16 + lr] = f2bf(gf);
                G0[gbase + 2*16 + lr] = f2bf(gg);
                G0[gbase + 3*16 + lr] = f2bf(go);
            } else {
                gi += bf2f(G0[gbase + 0*16 + lr]);
                gf += bf2f(G0[gbase + 1*16 + lr]);
                gg += bf2f(G0[gbase + 2*16 + lr]);
                go += bf2f(G0[gbase + 3*16 + lr]);
            }
            size_t cidx = (size_t)n * 1024 + j;
            float cprev = (MODE == 1) ? 0.0f : c_st[cidx];
            float cv = sigmoidf_(gf) * cprev + sigmoidf_(gi) * ftanh(gg);
            if (MODE != 2) c_st[cidx] = cv;
            float hn = sigmoidf_(go) * ftanh(cv);
            if (j < 512)
                h_bf[(size_t)n * 512 + j] = f2bf(qenc[(size_t)n * 512 + j] + hn);
        }
    }
}

// ---------------------------------------------------------------------------
// LayerNorm ddof=1, row length 512; fp32 + bf16 outputs
// ---------------------------------------------------------------------------
__global__ __launch_bounds__(256) void ln_kernel(
    const float* __restrict__ z, const float* __restrict__ a,
    const float* __restrict__ b, float* __restrict__ o,
    unsigned short* __restrict__ ob)
{
    __shared__ float red[256];
    int n = blockIdx.x, t = threadIdx.x;
    const float* zp = z + (long long)n * 512;
    float2 v = *(const float2*)(zp + t*2);
    red[t] = v.x + v.y;
    __syncthreads();
    for (int off = 128; off > 0; off >>= 1) {
        if (t < off) red[t] += red[t+off];
        __syncthreads();
    }
    float mu = red[0] * (1.0f/512.0f);
    __syncthreads();
    float d0 = v.x - mu, d1 = v.y - mu;
    red[t] = d0*d0 + d1*d1;
    __syncthreads();
    for (int off = 128; off > 0; off >>= 1) {
        if (t < off) red[t] += red[t+off];
        __syncthreads();
    }
    float var = red[0] * (1.0f/511.0f);
    float inv = 1.0f / (sqrtf(var) + 1e-3f);
    float r0 = d0 * inv * a[t*2]   + b[t*2];
    float r1 = d1 * inv * a[t*2+1] + b[t*2+1];
    float* op = o + (long long)n * 512;
    op[t*2] = r0; op[t*2+1] = r1;
    unsigned short* obp = ob + (long long)n * 512;
    obp[t*2] = f2bf(r0); obp[t*2+1] = f2bf(r1);
}

__global__ __launch_bounds__(256) void mean5_kernel(
    const float* __restrict__ se, float* __restrict__ sg)
{
    int d = blockIdx.x * 256 + threadIdx.x;
    if (d < 512) {
        float s = 0.0f;
        #pragma unroll
        for (int f = 0; f < 5; f++) s += se[f*512 + d];
        sg[d] = s * 0.2f;
    }
}

// svec_p[m'] = sum_k s_g[k] * W_hh[orig(m')][512+k]
__global__ __launch_bounds__(256) void svecg_kernel(
    const float* __restrict__ sg, const float* __restrict__ Whh,
    float* __restrict__ outv)
{
    __shared__ float sgl[512];
    int t = threadIdx.x;
    sgl[t] = sg[t]; sgl[256+t] = sg[256+t];
    __syncthreads();
    int mp = blockIdx.x * 256 + t;
    int orig = perm_orig(mp);
    const float* wp = Whh + (long long)orig * 1024 + 512;
    float s = 0.0f;
    for (int k = 0; k < 512; k += 4) {
        float4 wv = *(const float4*)(wp + k);
        s += sgl[k]*wv.x + sgl[k+1]*wv.y + sgl[k+2]*wv.z + sgl[k+3]*wv.w;
    }
    outv[mp] = s;
}

// out[n] = dot(h_bf[n], s_g)
__global__ __launch_bounds__(256) void dot_kernel(
    const unsigned short* __restrict__ h_bf, const float* __restrict__ sg,
    float* __restrict__ out)
{
    int w = threadIdx.x >> 6, lane = threadIdx.x & 63;
    int n = blockIdx.x * 4 + w;
    bf16x8 hv = *(const bf16x8*)(h_bf + (long long)n * 512 + lane * 8);
    const float* sp = sg + lane * 8;
    float4 b0 = *(const float4*)sp, b1 = *(const float4*)(sp+4);
    float bs[8] = {b0.x,b0.y,b0.z,b0.w,b1.x,b1.y,b1.z,b1.w};
    float p = 0.0f;
    #pragma unroll
    for (int q = 0; q < 8; q++) p += bf2f((unsigned short)hv[q]) * bs[q];
    #pragma unroll
    for (int off = 32; off > 0; off >>= 1) p += __shfl_down(p, off);
    if (lane == 0) out[n] = p;
}

extern "C" void kernel_launch(void* const* d_in, const int* in_sizes, int n_in,
                              void* d_out, int out_size, void* d_ws, size_t ws_size,
                              hipStream_t stream)
{
    (void)in_sizes; (void)n_in; (void)out_size; (void)ws_size;
    const float* emb       = (const float*)d_in[0];
    const float* gcn_W     = (const float*)d_in[1];
    const float* gcn_wb    = (const float*)d_in[2];
    const float* gcn_b     = (const float*)d_in[3];
    const float* gate_w    = (const float*)d_in[4];
    const float* gate_temp = (const float*)d_in[5];
    const float* p1_W      = (const float*)d_in[6];
    const float* p1_b      = (const float*)d_in[7];
    const float* p2_W      = (const float*)d_in[8];
    const float* p2_b      = (const float*)d_in[9];
    const float* ln_a      = (const float*)d_in[10];
    const float* ln_b      = (const float*)d_in[11];
    const float* W_ih      = (const float*)d_in[12];
    const float* W_hh      = (const float*)d_in[13];
    const float* b_ih      = (const float*)d_in[14];
    const float* b_hh      = (const float*)d_in[15];
    const int*   query     = (const int*)d_in[16];
    const int*   support   = (const int*)d_in[17];
    const int*   q_l1      = (const int*)d_in[18];
    const int*   q_deg_l   = (const int*)d_in[19];
    const int*   q_r1      = (const int*)d_in[20];
    const int*   q_deg_r   = (const int*)d_in[21];
    const int*   s_l1      = (const int*)d_in[22];
    const int*   s_deg_l   = (const int*)d_in[23];
    const int*   s_r1      = (const int*)d_in[24];
    const int*   s_deg_r   = (const int*)d_in[25];
    float* out = (float*)d_out;
    typedef unsigned short us;

    char* wp_ = (char*)d_ws;
    auto take = [&](size_t bytes) { void* p = wp_; wp_ += (bytes + 255) & ~(size_t)255; return p; };
    us*    vec_bf  = (us*)   take((size_t)2176*512*2);   // rows 0..2047 q, 2048..2052 s
    us*    h1_bf   = (us*)   take((size_t)2176*1024*2);
    float* z_buf   = (float*)take((size_t)2176*512*4);
    float* enc_f   = (float*)take((size_t)2176*512*4);
    us*    enc_bf  = (us*)   take((size_t)2176*512*2);
    float* s_g     = (float*)take(512*4);
    float* bias0_p = (float*)take(4096*4);
    float* svec_p  = (float*)take(4096*4);
    float* c_st    = (float*)take((size_t)2048*1024*4);
    us*    h_bf    = (us*)   take((size_t)2048*512*2);
    us*    wgcn    = (us*)   take((size_t)256*512*2);
    us*    p1w     = (us*)   take((size_t)1024*512*2);
    us*    p2w     = (us*)   take((size_t)512*1024*2);
    us*    wih_p   = (us*)   take((size_t)4096*512*2);
    us*    whh_p   = (us*)   take((size_t)4096*512*2);
    us*    G0_bf   = (us*)   take((size_t)2048*4096*2);

    // 1) weights -> bf16 (+ gate-interleave permutation for LSTM)
    preconvert<<<5252, 256, 0, stream>>>(gcn_W, p1_W, p2_W, W_ih, W_hh, b_ih, b_hh,
        wgcn, p1w, p2w, wih_p, whh_p, bias0_p);

    // 2) neighbor encoders (1 sample/block, 3 blocks/CU)
    ne_fused<<<4106, 256, 0, stream>>>(emb, wgcn, gcn_wb, gcn_b, gate_w, gate_temp,
        q_l1, q_deg_l, q_r1, q_deg_r, s_l1, s_deg_l, s_r1, s_deg_r,
        query, support, vec_bf);

    // 3) support encoder over q+s rows (N=2053): p1 relu -> p2 +resid -> LN
    mfma_gemm<1,0,1,0,1><<<dim3(8,17), 256, 0, stream>>>(vec_bf, p1w, p1_b, nullptr, nullptr, h1_bf, 2053, 1024, 512);
    mfma_gemm<1,1,0,1,0><<<dim3(4,17), 256, 0, stream>>>(h1_bf, p2w, p2_b, vec_bf, z_buf, nullptr, 2053, 512, 1024);
    ln_kernel<<<2053, 256, 0, stream>>>(z_buf, ln_a, ln_b, enc_f, enc_bf);
    mean5_kernel<<<2, 256, 0, stream>>>(enc_f + (size_t)2048*512, s_g);
    svecg_kernel<<<16, 256, 0, stream>>>(s_g, W_hh, svec_p);

    // 4) LSTM: G0 gemm + step-1 ew fused, 2 mid steps, last step halved
    lstm_gemm<1><<<dim3(32,16), 256, 0, stream>>>(enc_bf, wih_p, bias0_p, G0_bf, c_st, enc_f, h_bf);
    for (int s2 = 0; s2 < 2; s2++)
        lstm_gemm<0><<<dim3(32,16), 256, 0, stream>>>(h_bf, whh_p, svec_p, G0_bf, c_st, enc_f, h_bf);
    lstm_gemm<2><<<dim3(16,16), 256, 0, stream>>>(h_bf, whh_p, svec_p, G0_bf, c_st, enc_f, h_bf);

    // 5) final scores
    dot_kernel<<<512, 256, 0, stream>>>(h_bf, s_g, out);
}

// Round 3
// 812.391 us; speedup vs baseline: 1.1009x; 1.0419x over previous
//
#include <hip/hip_runtime.h>
#include <math.h>

#define PADID 400000

typedef __attribute__((ext_vector_type(8))) short bf16x8;
typedef __attribute__((ext_vector_type(4))) float f32x4;

__device__ __forceinline__ float sigmoidf_(float x){ return 1.0f/(1.0f+__expf(-x)); }
__device__ __forceinline__ float ftanh(float x){ return 1.0f - 2.0f/(__expf(2.0f*x)+1.0f); }

__device__ __forceinline__ unsigned short f2bf(float f){
    unsigned u = __float_as_uint(f);
    u += 0x7FFFu + ((u >> 16) & 1u);
    return (unsigned short)(u >> 16);
}
__device__ __forceinline__ float bf2f(unsigned short s){
    return __uint_as_float(((unsigned)s) << 16);
}

// gate-interleaved permutation: m' -> original gate-major row
// Only m' < 2048 (gate cols j < 512) are live: cols j>=512 of every LSTM
// gate are dead (h uses h_new[:, :512] only; c[:,512:] feeds only dead state).
__device__ __forceinline__ int perm_orig(int mp){
    int gate = (mp >> 4) & 3;
    int j = (mp >> 6) * 16 + (mp & 15);
    return gate * 1024 + j;
}

// ---------------------------------------------------------------------------
// Weight preconversion fp32 -> bf16 + permutations (one pass).
// Only live LSTM rows (m' < 2048) are converted.
// ---------------------------------------------------------------------------
__global__ __launch_bounds__(256) void preconvert(
    const float* __restrict__ gcnW, const float* __restrict__ p1W,
    const float* __restrict__ p2W, const float* __restrict__ Wih,
    const float* __restrict__ Whh, const float* __restrict__ b_ih,
    const float* __restrict__ b_hh,
    unsigned short* __restrict__ wgcn, unsigned short* __restrict__ p1w,
    unsigned short* __restrict__ p2w, unsigned short* __restrict__ wih_p,
    unsigned short* __restrict__ whh_p, float* __restrict__ bias0_p)
{
    long long i = ((long long)blockIdx.x * 256 + threadIdx.x) * 4;
    float4 v;
    if (i < 131072LL) {
        v = *(const float4*)(gcnW + i);
        unsigned a0 = f2bf(v.x) | ((unsigned)f2bf(v.y) << 16);
        unsigned a1 = f2bf(v.z) | ((unsigned)f2bf(v.w) << 16);
        *(uint2*)(wgcn + i) = make_uint2(a0, a1);
    } else if (i < 655360LL) {
        long long off = i - 131072LL;
        v = *(const float4*)(p1W + off);
        unsigned a0 = f2bf(v.x) | ((unsigned)f2bf(v.y) << 16);
        unsigned a1 = f2bf(v.z) | ((unsigned)f2bf(v.w) << 16);
        *(uint2*)(p1w + off) = make_uint2(a0, a1);
    } else if (i < 1179648LL) {
        long long off = i - 655360LL;
        v = *(const float4*)(p2W + off);
        unsigned a0 = f2bf(v.x) | ((unsigned)f2bf(v.y) << 16);
        unsigned a1 = f2bf(v.z) | ((unsigned)f2bf(v.w) << 16);
        *(uint2*)(p2w + off) = make_uint2(a0, a1);
    } else if (i < 2228224LL) {
        long long off = i - 1179648LL;           // Wih, m' < 2048
        int mp = (int)(off >> 9), col = (int)(off & 511);
        int orig = perm_orig(mp);
        v = *(const float4*)(Wih + (long long)orig * 512 + col);
        unsigned a0 = f2bf(v.x) | ((unsigned)f2bf(v.y) << 16);
        unsigned a1 = f2bf(v.z) | ((unsigned)f2bf(v.w) << 16);
        *(uint2*)(wih_p + off) = make_uint2(a0, a1);
    } else if (i < 3276800LL) {
        long long off = i - 2228224LL;           // Whh (h part), m' < 2048
        int mp = (int)(off >> 9), col = (int)(off & 511);
        int orig = perm_orig(mp);
        v = *(const float4*)(Whh + (long long)orig * 1024 + col);
        unsigned a0 = f2bf(v.x) | ((unsigned)f2bf(v.y) << 16);
        unsigned a1 = f2bf(v.z) | ((unsigned)f2bf(v.w) << 16);
        *(uint2*)(whh_p + off) = make_uint2(a0, a1);
    } else if (i < 3278848LL) {
        long long off = i - 3276800LL;           // bias, m' < 2048
        #pragma unroll
        for (int q = 0; q < 4; q++) {
            int mp = (int)off + q;
            int orig = perm_orig(mp);
            bias0_p[mp] = b_ih[orig] + b_hh[orig];
        }
    }
}

// ---------------------------------------------------------------------------
// Neighbor encoder, 1 sample/block. A = gathered emb rows (64 x 512 bf16),
// B = gcn_W bf16 (256 x 512). 4 waves, each computes all 64 rows x 64 cols.
// LDS ~47 KB -> 3 blocks/CU; acc[4][4] (64 VGPR) -> no spill risk.
// Rowsum reduction via in-wave kg-butterfly (no LDS red array).
// ---------------------------------------------------------------------------
__device__ __forceinline__ void ne_decode(int s,
    const int* q_l1, const int* q_deg_l, const int* q_r1, const int* q_deg_r,
    const int* s_l1, const int* s_deg_l, const int* s_r1, const int* s_deg_r,
    const int* query, const int* support,
    const int*& conn, const int*& deg, const int*& ids, int& n, int& ids_off, int& row, int& col)
{
    if (s < 2048)      { conn = q_l1; deg = q_deg_l; ids = query;   n = s;      ids_off = 0; row = s;        col = 0;   }
    else if (s < 4096) { conn = q_r1; deg = q_deg_r; ids = query;   n = s-2048; ids_off = 1; row = s-2048;   col = 256; }
    else if (s < 4101) { conn = s_l1; deg = s_deg_l; ids = support; n = s-4096; ids_off = 0; row = 2048+n;   col = 0;   }
    else               { conn = s_r1; deg = s_deg_r; ids = support; n = s-4101; ids_off = 1; row = 2048+n;   col = 256; }
}

__global__ __launch_bounds__(256, 3) void ne_fused(
    const float* __restrict__ emb, const unsigned short* __restrict__ Wbf,
    const float* __restrict__ wb, const float* __restrict__ bb,
    const float* __restrict__ gate_w, const float* __restrict__ gate_temp,
    const int* __restrict__ q_l1, const int* __restrict__ q_deg_l,
    const int* __restrict__ q_r1, const int* __restrict__ q_deg_r,
    const int* __restrict__ s_l1, const int* __restrict__ s_deg_l,
    const int* __restrict__ s_r1, const int* __restrict__ s_deg_r,
    const int* __restrict__ query, const int* __restrict__ support,
    unsigned short* __restrict__ vec_bf)
{
    __shared__ int   rel_s[64];
    __shared__ int   ent_s[64];
    __shared__ unsigned short A_lds[64 * 72];
    __shared__ unsigned short B_lds[256 * 72];
    __shared__ float gate_sh;

    const int t = threadIdx.x;
    const int lane = t & 63, w = t >> 6, lr = lane & 15, kg = lane >> 4;
    const int wc0 = w * 64;             // col base of this wave (0..192)

    // decode this block's sample
    const int *conn, *deg, *ids; int n, ids_off, row, col;
    ne_decode(blockIdx.x, q_l1,q_deg_l,q_r1,q_deg_r,s_l1,s_deg_l,s_r1,s_deg_r,
              query, support, conn, deg, ids, n, ids_off, row, col);

    // load conn (64 neighbors x {rel, ent})
    if (t < 128) {
        int v = conn[n*128 + t];
        if (t & 1) ent_s[t>>1] = v; else rel_s[t>>1] = v;
    }
    __syncthreads();

    const int arow = t >> 2, aq = t & 3;  // A-stage: row 0..63, quarter 0..3

    // ---- pipelined A-gather staging registers (16 floats / thread) ----
    float4 a_reg[4];
    #define ISSUE_A(ch_) { \
        const int side_ = ((ch_) >= 4); \
        const int cg0_ = ((ch_) & 3) * 64; \
        int rowid_ = side_ ? ent_s[arow] : rel_s[arow]; \
        const float* src_ = emb + (long long)rowid_ * 256 + cg0_ + aq * 16; \
        _Pragma("unroll") \
        for (int q_ = 0; q_ < 4; q_++) a_reg[q_] = *(const float4*)(src_ + q_*4); \
    }

    ISSUE_A(0);

    // gate: wave 0 gathers gate_w and reduces in-wave
    if (t < 64) {
        int r = rel_s[t];
        float gwv = gate_w[(r == PADID) ? 0 : r];
        #pragma unroll
        for (int off = 32; off > 0; off >>= 1) gwv += __shfl_down(gwv, off);
        if (t == 0) {
            float g = sigmoidf_((gwv * (1.0f/64.0f)) / gate_temp[0]);
            if (!((float)deg[n] > 0.0f)) g = 1.0f;
            gate_sh = g;
        }
    }

    f32x4 acc[4][4];
    #pragma unroll
    for (int i = 0; i < 4; i++)
        #pragma unroll
        for (int j = 0; j < 4; j++)
            acc[i][j] = (f32x4){0.f,0.f,0.f,0.f};

    for (int ch = 0; ch < 8; ch++) {
        // B stage: 256 rows x 64 cols bf16 copy (L2-resident)
        #pragma unroll
        for (int j = 0; j < 8; j++) {
            int brow = j * 32 + (t >> 3);
            bf16x8 v = *(const bf16x8*)(Wbf + (long long)brow * 512 + ch*64 + (t & 7) * 8);
            *(bf16x8*)&B_lds[brow*72 + (t & 7) * 8] = v;
        }
        // A stage: staged registers -> bf16 -> LDS (16 cols per thread)
        {
            unsigned short* dst = &A_lds[arow*72 + aq*16];
            bf16x8 o0, o1;
            o0[0]=(short)f2bf(a_reg[0].x); o0[1]=(short)f2bf(a_reg[0].y);
            o0[2]=(short)f2bf(a_reg[0].z); o0[3]=(short)f2bf(a_reg[0].w);
            o0[4]=(short)f2bf(a_reg[1].x); o0[5]=(short)f2bf(a_reg[1].y);
            o0[6]=(short)f2bf(a_reg[1].z); o0[7]=(short)f2bf(a_reg[1].w);
            o1[0]=(short)f2bf(a_reg[2].x); o1[1]=(short)f2bf(a_reg[2].y);
            o1[2]=(short)f2bf(a_reg[2].z); o1[3]=(short)f2bf(a_reg[2].w);
            o1[4]=(short)f2bf(a_reg[3].x); o1[5]=(short)f2bf(a_reg[3].y);
            o1[6]=(short)f2bf(a_reg[3].z); o1[7]=(short)f2bf(a_reg[3].w);
            *(bf16x8*)(dst)     = o0;
            *(bf16x8*)(dst + 8) = o1;
        }
        __syncthreads();
        // prefetch next channel's A rows while MFMA runs on this channel
        if (ch < 7) ISSUE_A(ch + 1);
        #pragma unroll
        for (int ks = 0; ks < 64; ks += 32) {
            bf16x8 a[4], b[4];
            #pragma unroll
            for (int rt = 0; rt < 4; rt++)
                a[rt] = *(const bf16x8*)&A_lds[(rt*16 + lr)*72 + ks + kg*8];
            #pragma unroll
            for (int ct = 0; ct < 4; ct++)
                b[ct] = *(const bf16x8*)&B_lds[(wc0 + ct*16 + lr)*72 + ks + kg*8];
            #pragma unroll
            for (int rt = 0; rt < 4; rt++)
                #pragma unroll
                for (int ct = 0; ct < 4; ct++)
                    acc[rt][ct] = __builtin_amdgcn_mfma_f32_16x16x32_bf16(a[rt], b[ct], acc[rt][ct], 0, 0, 0);
        }
        __syncthreads();
    }
    #undef ISSUE_A

    // epilogue: bias + leaky_relu + PAD mask + rowsum, kg-butterfly reduce
    float outv0, outv1, outv2, outv3;
    #pragma unroll
    for (int ct = 0; ct < 4; ct++) {
        int d = wc0 + ct*16 + lr;
        float bd = wb[d] + bb[d];
        float pp = 0.0f;
        #pragma unroll
        for (int rt = 0; rt < 4; rt++) {
            int rbase = rt*16 + kg*4;
            #pragma unroll
            for (int reg = 0; reg < 4; reg++) {
                if (rel_s[rbase + reg] != PADID) {
                    float v = acc[rt][ct][reg] + bd;
                    v = (v > 0.0f) ? v : 0.01f * v;
                    pp += v;
                }
            }
        }
        pp += __shfl_xor(pp, 16);
        pp += __shfl_xor(pp, 32);
        if (ct == 0) outv0 = pp; else if (ct == 1) outv1 = pp;
        else if (ct == 2) outv2 = pp; else outv3 = pp;
    }
    // lane writes col d = wc0 + kg*16 + lr  (its ct == kg value)
    float agg = (kg == 0) ? outv0 : (kg == 1) ? outv1 : (kg == 2) ? outv2 : outv3;
    int dcol = wc0 + kg*16 + lr;
    float degf = fmaxf((float)deg[n], 1.0f);
    agg /= degf;
    int id = ids[n*2 + ids_off];
    float o = ftanh(emb[(long long)id * 256 + dcol] + gate_sh * agg);
    vec_bf[(long long)row * 512 + col + dcol] = f2bf(o);
}

// ---------------------------------------------------------------------------
// Generic bf16 MFMA GEMM (support encoder): C = act(A.B^T + bias + add)
// 128x128 tile, BK=64, LDS stride 72.
// ---------------------------------------------------------------------------
template<int HB, int HADD, int RELU, int WF, int WB>
__global__ __launch_bounds__(256) void mfma_gemm(
    const unsigned short* __restrict__ A, const unsigned short* __restrict__ B,
    const float* __restrict__ bias, const unsigned short* __restrict__ addbf,
    float* __restrict__ Cf, unsigned short* __restrict__ Cb, int N, int M, int K)
{
    __shared__ unsigned short A_lds[128 * 72];
    __shared__ unsigned short B_lds[128 * 72];
    const int t = threadIdx.x;
    const int bm0 = blockIdx.x * 128, bn0 = blockIdx.y * 128;
    const int lane = t & 63, w = t >> 6, wn = w >> 1, wm = w & 1;
    const int lr = lane & 15, kg = lane >> 4;

    f32x4 acc[4][4];
    #pragma unroll
    for (int i = 0; i < 4; i++)
        #pragma unroll
        for (int j = 0; j < 4; j++)
            acc[i][j] = (f32x4){0.f,0.f,0.f,0.f};

    const int r = t >> 1, half = t & 1;
    const unsigned short* Ap = A + (size_t)(bn0 + r) * K + half * 32;
    const unsigned short* Bp = B + (size_t)(bm0 + r) * K + half * 32;
    unsigned short* Aw = &A_lds[r*72 + half*32];
    unsigned short* Bw = &B_lds[r*72 + half*32];

    for (int c0 = 0; c0 < K; c0 += 64) {
        #pragma unroll
        for (int q = 0; q < 4; q++) {
            *(bf16x8*)(Aw + q*8) = *(const bf16x8*)(Ap + c0 + q*8);
            *(bf16x8*)(Bw + q*8) = *(const bf16x8*)(Bp + c0 + q*8);
        }
        __syncthreads();
        #pragma unroll
        for (int ks = 0; ks < 64; ks += 32) {
            bf16x8 a[4], b[4];
            #pragma unroll
            for (int rt = 0; rt < 4; rt++)
                a[rt] = *(const bf16x8*)&A_lds[(wn*64 + rt*16 + lr)*72 + ks + kg*8];
            #pragma unroll
            for (int ct = 0; ct < 4; ct++)
                b[ct] = *(const bf16x8*)&B_lds[(wm*64 + ct*16 + lr)*72 + ks + kg*8];
            #pragma unroll
            for (int rt = 0; rt < 4; rt++)
                #pragma unroll
                for (int ct = 0; ct < 4; ct++)
                    acc[rt][ct] = __builtin_amdgcn_mfma_f32_16x16x32_bf16(a[rt], b[ct], acc[rt][ct], 0, 0, 0);
        }
        __syncthreads();
    }

    float bsum[4];
    #pragma unroll
    for (int ct = 0; ct < 4; ct++)
        bsum[ct] = HB ? bias[bm0 + wm*64 + ct*16 + lr] : 0.0f;
    #pragma unroll
    for (int rt = 0; rt < 4; rt++) {
        #pragma unroll
        for (int reg = 0; reg < 4; reg++) {
            int n = bn0 + wn*64 + rt*16 + kg*4 + reg;
            if (n < N) {
                size_t rowb = (size_t)n * M + bm0 + wm*64;
                #pragma unroll
                for (int ct = 0; ct < 4; ct++) {
                    size_t idx = rowb + ct*16 + lr;
                    float v = acc[rt][ct][reg] + bsum[ct];
                    if (HADD) v += bf2f(addbf[idx]);
                    if (RELU) v = fmaxf(v, 0.0f);
                    if (WF) Cf[idx] = v;
                    if (WB) Cb[idx] = f2bf(v);
                }
            }
        }
    }
}

// ---------------------------------------------------------------------------
// LSTM GEMM with fused elementwise. Gate-interleaved layout (perm m'),
// only live columns m' < 2048 (gate cols j < 512). M = 2048, grid (16,16).
// MODE 1 (FIRST): gates = A.B^T + bias0_p; writes G0_bf, c=si*tanh(g), h.
// MODE 0 (MID):   gates = A.B^T + svec_p + bf(G0); c = sf*c + si*tanh(g); h.
// MODE 2 (LAST):  like MID but c is not stored (never consumed again).
// ---------------------------------------------------------------------------
template<int MODE>
__global__ __launch_bounds__(256, 2) void lstm_gemm(
    const unsigned short* __restrict__ A, const unsigned short* __restrict__ B,
    const float* __restrict__ biasv, unsigned short* __restrict__ G0,
    float* __restrict__ c_st, const float* __restrict__ qenc,
    unsigned short* __restrict__ h_bf)
{
    __shared__ unsigned short A_lds[128 * 72];
    __shared__ unsigned short B_lds[128 * 72];
    const int t = threadIdx.x;
    const int bm0 = blockIdx.x * 128, bn0 = blockIdx.y * 128;
    const int lane = t & 63, w = t >> 6, wn = w >> 1, wm = w & 1;
    const int lr = lane & 15, kg = lane >> 4;

    f32x4 acc[4][4];
    #pragma unroll
    for (int i = 0; i < 4; i++)
        #pragma unroll
        for (int j = 0; j < 4; j++)
            acc[i][j] = (f32x4){0.f,0.f,0.f,0.f};

    const int r = t >> 1, half = t & 1;
    const unsigned short* Ap = A + (size_t)(bn0 + r) * 512 + half * 32;
    const unsigned short* Bp = B + (size_t)(bm0 + r) * 512 + half * 32;
    unsigned short* Aw = &A_lds[r*72 + half*32];
    unsigned short* Bw = &B_lds[r*72 + half*32];

    for (int c0 = 0; c0 < 512; c0 += 64) {
        #pragma unroll
        for (int q = 0; q < 4; q++) {
            *(bf16x8*)(Aw + q*8) = *(const bf16x8*)(Ap + c0 + q*8);
            *(bf16x8*)(Bw + q*8) = *(const bf16x8*)(Bp + c0 + q*8);
        }
        __syncthreads();
        #pragma unroll
        for (int ks = 0; ks < 64; ks += 32) {
            bf16x8 a[4], b[4];
            #pragma unroll
            for (int rt = 0; rt < 4; rt++)
                a[rt] = *(const bf16x8*)&A_lds[(wn*64 + rt*16 + lr)*72 + ks + kg*8];
            #pragma unroll
            for (int ct = 0; ct < 4; ct++)
                b[ct] = *(const bf16x8*)&B_lds[(wm*64 + ct*16 + lr)*72 + ks + kg*8];
            #pragma unroll
            for (int rt = 0; rt < 4; rt++)
                #pragma unroll
                for (int ct = 0; ct < 4; ct++)
                    acc[rt][ct] = __builtin_amdgcn_mfma_f32_16x16x32_bf16(a[rt], b[ct], acc[rt][ct], 0, 0, 0);
        }
        __syncthreads();
    }

    const int g0col = (bm0 + wm*64) >> 6;     // 0..31
    const int j = g0col*16 + lr;              // 0..511
    float e[4];
    #pragma unroll
    for (int ct = 0; ct < 4; ct++)
        e[ct] = biasv[bm0 + wm*64 + ct*16 + lr];

    #pragma unroll
    for (int rt = 0; rt < 4; rt++) {
        #pragma unroll
        for (int reg = 0; reg < 4; reg++) {
            int n = bn0 + wn*64 + rt*16 + kg*4 + reg;
            size_t gbase = (size_t)n * 2048 + bm0 + wm*64;
            float gi = acc[rt][0][reg] + e[0];
            float gf = acc[rt][1][reg] + e[1];
            float gg = acc[rt][2][reg] + e[2];
            float go = acc[rt][3][reg] + e[3];
            if (MODE == 1) {
                G0[gbase + 0*16 + lr] = f2bf(gi);
                G0[gbase + 1*16 + lr] = f2bf(gf);
                G0[gbase + 2*16 + lr] = f2bf(gg);
                G0[gbase + 3*16 + lr] = f2bf(go);
            } else {
                gi += bf2f(G0[gbase + 0*16 + lr]);
                gf += bf2f(G0[gbase + 1*16 + lr]);
                gg += bf2f(G0[gbase + 2*16 + lr]);
                go += bf2f(G0[gbase + 3*16 + lr]);
            }
            size_t cidx = (size_t)n * 512 + j;
            float cprev = (MODE == 1) ? 0.0f : c_st[cidx];
            float cv = sigmoidf_(gf) * cprev + sigmoidf_(gi) * ftanh(gg);
            if (MODE != 2) c_st[cidx] = cv;
            float hn = sigmoidf_(go) * ftanh(cv);
            h_bf[(size_t)n * 512 + j] = f2bf(qenc[(size_t)n * 512 + j] + hn);
        }
    }
}

// ---------------------------------------------------------------------------
// LayerNorm ddof=1, row length 512; fp32 + bf16 outputs
// ---------------------------------------------------------------------------
__global__ __launch_bounds__(256) void ln_kernel(
    const float* __restrict__ z, const float* __restrict__ a,
    const float* __restrict__ b, float* __restrict__ o,
    unsigned short* __restrict__ ob)
{
    __shared__ float red[256];
    int n = blockIdx.x, t = threadIdx.x;
    const float* zp = z + (long long)n * 512;
    float2 v = *(const float2*)(zp + t*2);
    red[t] = v.x + v.y;
    __syncthreads();
    for (int off = 128; off > 0; off >>= 1) {
        if (t < off) red[t] += red[t+off];
        __syncthreads();
    }
    float mu = red[0] * (1.0f/512.0f);
    __syncthreads();
    float d0 = v.x - mu, d1 = v.y - mu;
    red[t] = d0*d0 + d1*d1;
    __syncthreads();
    for (int off = 128; off > 0; off >>= 1) {
        if (t < off) red[t] += red[t+off];
        __syncthreads();
    }
    float var = red[0] * (1.0f/511.0f);
    float inv = 1.0f / (sqrtf(var) + 1e-3f);
    float r0 = d0 * inv * a[t*2]   + b[t*2];
    float r1 = d1 * inv * a[t*2+1] + b[t*2+1];
    float* op = o + (long long)n * 512;
    op[t*2] = r0; op[t*2+1] = r1;
    unsigned short* obp = ob + (long long)n * 512;
    obp[t*2] = f2bf(r0); obp[t*2+1] = f2bf(r1);
}

__global__ __launch_bounds__(256) void mean5_kernel(
    const float* __restrict__ se, float* __restrict__ sg)
{
    int d = blockIdx.x * 256 + threadIdx.x;
    if (d < 512) {
        float s = 0.0f;
        #pragma unroll
        for (int f = 0; f < 5; f++) s += se[f*512 + d];
        sg[d] = s * 0.2f;
    }
}

// svec_p[m'] = sum_k s_g[k] * W_hh[orig(m')][512+k], m' < 2048
__global__ __launch_bounds__(256) void svecg_kernel(
    const float* __restrict__ sg, const float* __restrict__ Whh,
    float* __restrict__ outv)
{
    __shared__ float sgl[512];
    int t = threadIdx.x;
    sgl[t] = sg[t]; sgl[256+t] = sg[256+t];
    __syncthreads();
    int mp = blockIdx.x * 256 + t;
    int orig = perm_orig(mp);
    const float* wp = Whh + (long long)orig * 1024 + 512;
    float s = 0.0f;
    for (int k = 0; k < 512; k += 4) {
        float4 wv = *(const float4*)(wp + k);
        s += sgl[k]*wv.x + sgl[k+1]*wv.y + sgl[k+2]*wv.z + sgl[k+3]*wv.w;
    }
    outv[mp] = s;
}

// out[n] = dot(h_bf[n], s_g)
__global__ __launch_bounds__(256) void dot_kernel(
    const unsigned short* __restrict__ h_bf, const float* __restrict__ sg,
    float* __restrict__ out)
{
    int w = threadIdx.x >> 6, lane = threadIdx.x & 63;
    int n = blockIdx.x * 4 + w;
    bf16x8 hv = *(const bf16x8*)(h_bf + (long long)n * 512 + lane * 8);
    const float* sp = sg + lane * 8;
    float4 b0 = *(const float4*)sp, b1 = *(const float4*)(sp+4);
    float bs[8] = {b0.x,b0.y,b0.z,b0.w,b1.x,b1.y,b1.z,b1.w};
    float p = 0.0f;
    #pragma unroll
    for (int q = 0; q < 8; q++) p += bf2f((unsigned short)hv[q]) * bs[q];
    #pragma unroll
    for (int off = 32; off > 0; off >>= 1) p += __shfl_down(p, off);
    if (lane == 0) out[n] = p;
}

extern "C" void kernel_launch(void* const* d_in, const int* in_sizes, int n_in,
                              void* d_out, int out_size, void* d_ws, size_t ws_size,
                              hipStream_t stream)
{
    (void)in_sizes; (void)n_in; (void)out_size; (void)ws_size;
    const float* emb       = (const float*)d_in[0];
    const float* gcn_W     = (const float*)d_in[1];
    const float* gcn_wb    = (const float*)d_in[2];
    const float* gcn_b     = (const float*)d_in[3];
    const float* gate_w    = (const float*)d_in[4];
    const float* gate_temp = (const float*)d_in[5];
    const float* p1_W      = (const float*)d_in[6];
    const float* p1_b      = (const float*)d_in[7];
    const float* p2_W      = (const float*)d_in[8];
    const float* p2_b      = (const float*)d_in[9];
    const float* ln_a      = (const float*)d_in[10];
    const float* ln_b      = (const float*)d_in[11];
    const float* W_ih      = (const float*)d_in[12];
    const float* W_hh      = (const float*)d_in[13];
    const float* b_ih      = (const float*)d_in[14];
    const float* b_hh      = (const float*)d_in[15];
    const int*   query     = (const int*)d_in[16];
    const int*   support   = (const int*)d_in[17];
    const int*   q_l1      = (const int*)d_in[18];
    const int*   q_deg_l   = (const int*)d_in[19];
    const int*   q_r1      = (const int*)d_in[20];
    const int*   q_deg_r   = (const int*)d_in[21];
    const int*   s_l1      = (const int*)d_in[22];
    const int*   s_deg_l   = (const int*)d_in[23];
    const int*   s_r1      = (const int*)d_in[24];
    const int*   s_deg_r   = (const int*)d_in[25];
    float* out = (float*)d_out;
    typedef unsigned short us;

    char* wp_ = (char*)d_ws;
    auto take = [&](size_t bytes) { void* p = wp_; wp_ += (bytes + 255) & ~(size_t)255; return p; };
    us*    vec_bf  = (us*)   take((size_t)2176*512*2);   // rows 0..2047 q, 2048..2052 s
    us*    h1_bf   = (us*)   take((size_t)2176*1024*2);
    float* z_buf   = (float*)take((size_t)2176*512*4);
    float* enc_f   = (float*)take((size_t)2176*512*4);
    us*    enc_bf  = (us*)   take((size_t)2176*512*2);
    float* s_g     = (float*)take(512*4);
    float* bias0_p = (float*)take(2048*4);
    float* svec_p  = (float*)take(2048*4);
    float* c_st    = (float*)take((size_t)2048*512*4);
    us*    h_bf    = (us*)   take((size_t)2048*512*2);
    us*    wgcn    = (us*)   take((size_t)256*512*2);
    us*    p1w     = (us*)   take((size_t)1024*512*2);
    us*    p2w     = (us*)   take((size_t)512*1024*2);
    us*    wih_p   = (us*)   take((size_t)2048*512*2);
    us*    whh_p   = (us*)   take((size_t)2048*512*2);
    us*    G0_bf   = (us*)   take((size_t)2048*2048*2);

    // 1) weights -> bf16 (+ gate-interleave permutation, live rows only)
    preconvert<<<3202, 256, 0, stream>>>(gcn_W, p1_W, p2_W, W_ih, W_hh, b_ih, b_hh,
        wgcn, p1w, p2w, wih_p, whh_p, bias0_p);

    // 2) neighbor encoders (1 sample/block, 3 blocks/CU)
    ne_fused<<<4106, 256, 0, stream>>>(emb, wgcn, gcn_wb, gcn_b, gate_w, gate_temp,
        q_l1, q_deg_l, q_r1, q_deg_r, s_l1, s_deg_l, s_r1, s_deg_r,
        query, support, vec_bf);

    // 3) support encoder over q+s rows (N=2053): p1 relu -> p2 +resid -> LN
    mfma_gemm<1,0,1,0,1><<<dim3(8,17), 256, 0, stream>>>(vec_bf, p1w, p1_b, nullptr, nullptr, h1_bf, 2053, 1024, 512);
    mfma_gemm<1,1,0,1,0><<<dim3(4,17), 256, 0, stream>>>(h1_bf, p2w, p2_b, vec_bf, z_buf, nullptr, 2053, 512, 1024);
    ln_kernel<<<2053, 256, 0, stream>>>(z_buf, ln_a, ln_b, enc_f, enc_bf);
    mean5_kernel<<<2, 256, 0, stream>>>(enc_f + (size_t)2048*512, s_g);
    svecg_kernel<<<8, 256, 0, stream>>>(s_g, W_hh, svec_p);

    // 4) LSTM over live cols only (M=2048): G0 gemm + step-1 ew, 2 mid, last
    lstm_gemm<1><<<dim3(16,16), 256, 0, stream>>>(enc_bf, wih_p, bias0_p, G0_bf, c_st, enc_f, h_bf);
    for (int s2 = 0; s2 < 2; s2++)
        lstm_gemm<0><<<dim3(16,16), 256, 0, stream>>>(h_bf, whh_p, svec_p, G0_bf, c_st, enc_f, h_bf);
    lstm_gemm<2><<<dim3(16,16), 256, 0, stream>>>(h_bf, whh_p, svec_p, G0_bf, c_st, enc_f, h_bf);

    // 5) final scores
    dot_kernel<<<512, 256, 0, stream>>>(h_bf, s_g, out);
}